// Round 13
// baseline (496.577 us; speedup 1.0000x reference)
//
#include <hip/hip_runtime.h>

typedef __bf16 bf16_t;
typedef __bf16 bf16x8 __attribute__((ext_vector_type(8)));
typedef __bf16 bf16x4 __attribute__((ext_vector_type(4)));
typedef float  f32x4  __attribute__((ext_vector_type(4)));
typedef float  f32x16 __attribute__((ext_vector_type(16)));
typedef unsigned int u32x4 __attribute__((ext_vector_type(4)));

#define N_HEADS 32
#define N_KVH   8
#define HEADDIM 128
#define WINDOW  512
#define NBATCH  4
#define SEQLEN  1024
#define NTOK    (NBATCH * SEQLEN)
#define HIDDEN  4096
#define KVW     2048   /* K|V row width: 1024 K + 1024 V */

// async global->LDS, 16B per lane. LDS dest is wave-uniform base + lane*16.
__device__ __forceinline__ void llds16(const bf16_t* g, const bf16_t* l)
{
    __builtin_amdgcn_global_load_lds(
        (const __attribute__((address_space(1))) void*)g,
        (__attribute__((address_space(3))) void*)l, 16, 0, 0);
}

#define MFMA16(a, b, c) __builtin_amdgcn_mfma_f32_16x16x32_bf16((a), (b), (c), 0, 0, 0)

// ---------------------------------------------------------------------------
// 8-phase 256x256 GEMM (r11/r12-verified): ~1.5 PF at tail-free grids
// (1 block/CU). Used for Q-proj (grid 256), KV-proj (grid 128), out-proj
// (grid 256). QKV-as-one (grid 384 = 1.5 rounds) measured WORSE (r11) --
// hence the Q/KV split.
// ---------------------------------------------------------------------------
template<bool OUT_F32>
__global__ __launch_bounds__(512, 2)
void gemm8p_kernel(const bf16_t* __restrict__ A, const bf16_t* __restrict__ Bt,
                   void* __restrict__ Cp, int M, int N, int K)
{
    __shared__ __align__(16) char lds[131072];   // 2 bufs x (A 32KB + B 32KB)
    const int tid  = threadIdx.x;
    const int w    = tid >> 6, lane = tid & 63;
    const int ntx  = N >> 8;
    const int nwg  = gridDim.x;
    const int cpx  = nwg >> 3;
    const int lin  = blockIdx.x;
    const int swz  = (nwg & 7) == 0 ? (lin & 7) * cpx + (lin >> 3) : lin;
    const int m0   = (swz / ntx) * 256;
    const int n0   = (swz % ntx) * 256;
    const int wm   = (w >> 2) * 128;     // 2 M groups of 128 rows
    const int wn   = (w & 3) * 64;       // 4 N groups of 64 cols
    const int fr   = lane & 15, g4 = lane >> 4;
    const int nk   = K >> 6;             // K-tiles of 64

    const int sl0 = (((0 + g4) ^ (fr & 7)) << 4);
    const int sl1 = (((4 + g4) ^ (fr & 7)) << 4);
    const int rs  = lane >> 3;
    const int ssb = (((lane & 7) ^ rs) << 3);

    const bf16_t* aS = A  + (size_t)(m0 + w * 16 + rs) * K + ssb;
    const bf16_t* bS = Bt + (size_t)(n0 + w * 16 + rs) * K + ssb;
    const size_t h128 = (size_t)128 * K;
    const size_t j8   = (size_t)8 * K;

    f32x4 acc[8][4];
#pragma unroll
    for (int i = 0; i < 8; ++i)
#pragma unroll
        for (int j = 0; j < 4; ++j) {
            acc[i][j][0] = 0.f; acc[i][j][1] = 0.f;
            acc[i][j][2] = 0.f; acc[i][j][3] = 0.f;
        }

    auto STG = [&](int buf, int which, int t) {
        char* dst = lds + buf * 65536 + which * 16384 + w * 2048;
        const bf16_t* src = ((which < 2) ? aS : bS)
                          + (size_t)(which & 1) * h128 + ((size_t)t << 6);
        llds16(src,      (const bf16_t*)dst);
        llds16(src + j8, (const bf16_t*)(dst + 1024));
    };

    STG(0, 0, 0); STG(0, 1, 0); STG(0, 2, 0); STG(0, 3, 0);
    if (nk > 1) {
        STG(1, 2, 1); STG(1, 3, 1);
        asm volatile("s_waitcnt vmcnt(4)" ::: "memory");
    } else {
        asm volatile("s_waitcnt vmcnt(0)" ::: "memory");
    }
    __builtin_amdgcn_sched_barrier(0);
    __builtin_amdgcn_s_barrier();
    __builtin_amdgcn_sched_barrier(0);

    bf16x8 aq[4][2], bl[2][2], bh[2][2];

    for (int t = 0; t < nk; ++t) {
        const int X = t & 1;
        const char* Ab = lds + X * 65536;
        const char* Bb = Ab + 32768;

        // q0: m0-3 x n0-1
#pragma unroll
        for (int mt = 0; mt < 4; ++mt) {
            const char* p = Ab + (wm + mt * 16 + fr) * 128;
            aq[mt][0] = *(const bf16x8*)(p + sl0);
            aq[mt][1] = *(const bf16x8*)(p + sl1);
        }
#pragma unroll
        for (int nt = 0; nt < 2; ++nt) {
            const char* p = Bb + (wn + nt * 16 + fr) * 128;
            bl[nt][0] = *(const bf16x8*)(p + sl0);
            bl[nt][1] = *(const bf16x8*)(p + sl1);
        }
        if (t + 1 < nk) STG(1 - X, 0, t + 1);
        __builtin_amdgcn_s_barrier();
        asm volatile("s_waitcnt lgkmcnt(0)" ::: "memory");
        __builtin_amdgcn_sched_barrier(0);
        __builtin_amdgcn_s_setprio(1);
#pragma unroll
        for (int mt = 0; mt < 4; ++mt)
#pragma unroll
            for (int nt = 0; nt < 2; ++nt) {
                acc[mt][nt] = MFMA16(aq[mt][0], bl[nt][0], acc[mt][nt]);
                acc[mt][nt] = MFMA16(aq[mt][1], bl[nt][1], acc[mt][nt]);
            }
        __builtin_amdgcn_s_setprio(0);
        __builtin_amdgcn_s_barrier();
        __builtin_amdgcn_sched_barrier(0);

        // q1: m0-3 x n2-3
#pragma unroll
        for (int nt = 0; nt < 2; ++nt) {
            const char* p = Bb + (wn + (nt + 2) * 16 + fr) * 128;
            bh[nt][0] = *(const bf16x8*)(p + sl0);
            bh[nt][1] = *(const bf16x8*)(p + sl1);
        }
        if (t + 1 < nk) STG(1 - X, 1, t + 1);
        __builtin_amdgcn_s_barrier();
        asm volatile("s_waitcnt lgkmcnt(0)" ::: "memory");
        __builtin_amdgcn_sched_barrier(0);
        __builtin_amdgcn_s_setprio(1);
#pragma unroll
        for (int mt = 0; mt < 4; ++mt)
#pragma unroll
            for (int nt = 0; nt < 2; ++nt) {
                acc[mt][nt + 2] = MFMA16(aq[mt][0], bh[nt][0], acc[mt][nt + 2]);
                acc[mt][nt + 2] = MFMA16(aq[mt][1], bh[nt][1], acc[mt][nt + 2]);
            }
        __builtin_amdgcn_s_setprio(0);
        __builtin_amdgcn_s_barrier();
        __builtin_amdgcn_sched_barrier(0);

        // q2: m4-7 x n0-1 (Blo held)
#pragma unroll
        for (int mt = 0; mt < 4; ++mt) {
            const char* p = Ab + (wm + (mt + 4) * 16 + fr) * 128;
            aq[mt][0] = *(const bf16x8*)(p + sl0);
            aq[mt][1] = *(const bf16x8*)(p + sl1);
        }
        if (t + 2 < nk) STG(X, 2, t + 2);
        __builtin_amdgcn_s_barrier();
        asm volatile("s_waitcnt lgkmcnt(0)" ::: "memory");
        __builtin_amdgcn_sched_barrier(0);
        __builtin_amdgcn_s_setprio(1);
#pragma unroll
        for (int mt = 0; mt < 4; ++mt)
#pragma unroll
            for (int nt = 0; nt < 2; ++nt) {
                acc[mt + 4][nt] = MFMA16(aq[mt][0], bl[nt][0], acc[mt + 4][nt]);
                acc[mt + 4][nt] = MFMA16(aq[mt][1], bl[nt][1], acc[mt + 4][nt]);
            }
        __builtin_amdgcn_s_setprio(0);
        __builtin_amdgcn_s_barrier();
        __builtin_amdgcn_sched_barrier(0);

        // q3: m4-7 x n2-3 (all regs held)
        if (t + 2 < nk) STG(X, 3, t + 2);
        __builtin_amdgcn_s_barrier();
        __builtin_amdgcn_sched_barrier(0);
        __builtin_amdgcn_s_setprio(1);
#pragma unroll
        for (int mt = 0; mt < 4; ++mt)
#pragma unroll
            for (int nt = 0; nt < 2; ++nt) {
                acc[mt + 4][nt + 2] = MFMA16(aq[mt][0], bh[nt][0], acc[mt + 4][nt + 2]);
                acc[mt + 4][nt + 2] = MFMA16(aq[mt][1], bh[nt][1], acc[mt + 4][nt + 2]);
            }
        __builtin_amdgcn_s_setprio(0);
        if (t + 1 < nk) {
            if (t + 2 < nk) asm volatile("s_waitcnt vmcnt(4)" ::: "memory");
            else            asm volatile("s_waitcnt vmcnt(0)" ::: "memory");
        }
        __builtin_amdgcn_sched_barrier(0);
        __builtin_amdgcn_s_barrier();
        __builtin_amdgcn_sched_barrier(0);
    }

    const int r0 = g4 << 2;
#pragma unroll
    for (int mt = 0; mt < 8; ++mt)
#pragma unroll
        for (int nt = 0; nt < 4; ++nt)
#pragma unroll
            for (int r = 0; r < 4; ++r) {
                int row = m0 + wm + mt * 16 + r0 + r;
                int col = n0 + wn + nt * 16 + fr;
                if constexpr (OUT_F32)
                    ((float*)Cp)[(size_t)row * N + col] = acc[mt][nt][r];
                else
                    ((bf16_t*)Cp)[(size_t)row * N + col] = (bf16_t)acc[mt][nt][r];
            }
}

// ---------------------------------------------------------------------------
// fallback GEMM: A f32 or bf16, B f32 [K][N] transposed in LDS
// ---------------------------------------------------------------------------
template<bool A_F32, bool OUT_F32>
__global__ __launch_bounds__(256)
void gemm_kernel(const void* __restrict__ Ap, const void* __restrict__ Bp,
                 void* __restrict__ Cp, int M, int N, int K)
{
    __shared__ bf16_t As[128 * 40];
    __shared__ bf16_t Bs[128 * 40];
    const int tid  = threadIdx.x;
    const int m0   = blockIdx.y * 128;
    const int n0   = blockIdx.x * 128;
    const int wave = tid >> 6, lane = tid & 63;
    const int wm   = (wave >> 1) * 64, wn = (wave & 1) * 64;
    const int fr   = lane & 15;
    const int koff = (lane >> 4) * 8;

    f32x4 acc[4][4];
#pragma unroll
    for (int i = 0; i < 4; ++i)
#pragma unroll
        for (int j = 0; j < 4; ++j) {
            acc[i][j][0] = 0.f; acc[i][j][1] = 0.f;
            acc[i][j][2] = 0.f; acc[i][j][3] = 0.f;
        }

    for (int kt = 0; kt < K; kt += 32) {
        __syncthreads();
        if constexpr (A_F32) {
            const float* A = (const float*)Ap;
#pragma unroll
            for (int i = 0; i < 4; ++i) {
                int lin = tid + i * 256;
                int row = lin >> 3;
                int kq  = (lin & 7) << 2;
                const float4 v = *(const float4*)(A + (size_t)(m0 + row) * K + kt + kq);
                bf16_t* d = &As[row * 40 + kq];
                d[0] = (bf16_t)v.x; d[1] = (bf16_t)v.y;
                d[2] = (bf16_t)v.z; d[3] = (bf16_t)v.w;
            }
        } else {
            const bf16_t* A = (const bf16_t*)Ap;
#pragma unroll
            for (int i = 0; i < 2; ++i) {
                int lin = tid + i * 256;
                int row = lin >> 2;
                int kq  = (lin & 3) << 3;
                *(bf16x8*)&As[row * 40 + kq] =
                    *(const bf16x8*)(A + (size_t)(m0 + row) * K + kt + kq);
            }
        }
        {
            const float* B = (const float*)Bp;
#pragma unroll
            for (int i = 0; i < 4; ++i) {
                int lin = tid + i * 256;
                int kr  = lin >> 5;
                int nc  = (lin & 31) << 2;
                const float4 v = *(const float4*)(B + (size_t)(kt + kr) * N + n0 + nc);
                Bs[(nc + 0) * 40 + kr] = (bf16_t)v.x;
                Bs[(nc + 1) * 40 + kr] = (bf16_t)v.y;
                Bs[(nc + 2) * 40 + kr] = (bf16_t)v.z;
                Bs[(nc + 3) * 40 + kr] = (bf16_t)v.w;
            }
        }
        __syncthreads();
        bf16x8 af[4], bfg[4];
#pragma unroll
        for (int mt = 0; mt < 4; ++mt)
            af[mt] = *(const bf16x8*)&As[(wm + mt * 16 + fr) * 40 + koff];
#pragma unroll
        for (int nt = 0; nt < 4; ++nt)
            bfg[nt] = *(const bf16x8*)&Bs[(wn + nt * 16 + fr) * 40 + koff];
#pragma unroll
        for (int mt = 0; mt < 4; ++mt)
#pragma unroll
            for (int nt = 0; nt < 4; ++nt)
                acc[mt][nt] = MFMA16(af[mt], bfg[nt], acc[mt][nt]);
    }
    const int r0 = (lane >> 4) << 2;
#pragma unroll
    for (int mt = 0; mt < 4; ++mt)
#pragma unroll
        for (int nt = 0; nt < 4; ++nt)
#pragma unroll
            for (int r = 0; r < 4; ++r) {
                int row = m0 + wm + mt * 16 + r0 + r;
                int col = n0 + wn + nt * 16 + fr;
                if constexpr (OUT_F32)
                    ((float*)Cp)[(size_t)row * N + col] = acc[mt][nt][r];
                else
                    ((bf16_t*)Cp)[(size_t)row * N + col] = (bf16_t)acc[mt][nt][r];
            }
}

// ---------------------------------------------------------------------------
// Merged prep: x f32->bf16 + Wq/Wk/Wv (+Wo) transpose-convert (r10-verified).
// ---------------------------------------------------------------------------
__global__ __launch_bounds__(256)
void prep_kernel(const float* __restrict__ x,
                 const float* __restrict__ Wq, const float* __restrict__ Wk,
                 const float* __restrict__ Wv, const float* __restrict__ Wo,
                 bf16_t* __restrict__ Xb, bf16_t* __restrict__ Wqkvt,
                 bf16_t* __restrict__ WoT)
{
    __shared__ bf16_t tile[32][33];
    const int bid = blockIdx.x;
    if (bid < 8192) {
        int i = bid * 256 + threadIdx.x;
        const float4 a = *(const float4*)(x + (size_t)i * 8);
        const float4 b = *(const float4*)(x + (size_t)i * 8 + 4);
        bf16x8 v;
        v[0] = (bf16_t)a.x; v[1] = (bf16_t)a.y; v[2] = (bf16_t)a.z; v[3] = (bf16_t)a.w;
        v[4] = (bf16_t)b.x; v[5] = (bf16_t)b.y; v[6] = (bf16_t)b.z; v[7] = (bf16_t)b.w;
        *(bf16x8*)(Xb + (size_t)i * 8) = v;
        return;
    }
    const float* W; bf16_t* Wt; int j;
    if (bid < 24576)      { W = Wq; Wt = Wqkvt;                          j = bid - 8192; }
    else if (bid < 28672) { W = Wk; Wt = Wqkvt + (size_t)4096 * HIDDEN;  j = bid - 24576; }
    else if (bid < 32768) { W = Wv; Wt = Wqkvt + (size_t)5120 * HIDDEN;  j = bid - 28672; }
    else                  { W = Wo; Wt = WoT;                            j = bid - 32768; }
    const int N  = (bid >= 24576 && bid < 32768) ? 1024 : HIDDEN;
    const int k0 = (j & 127) << 5;
    const int n0 = (j >> 7) << 5;
    const int c  = threadIdx.x & 31, r0 = threadIdx.x >> 5;
#pragma unroll
    for (int i = 0; i < 4; ++i) {
        int r = r0 + i * 8;
        tile[r][c] = (bf16_t)W[(size_t)(k0 + r) * N + n0 + c];
    }
    __syncthreads();
#pragma unroll
    for (int i = 0; i < 4; ++i) {
        int r = r0 + i * 8;
        Wt[(size_t)(n0 + r) * HIDDEN + k0 + c] = tile[c][r];
    }
}

__global__ __launch_bounds__(256)
void wtrans_kernel(const float* __restrict__ W, bf16_t* __restrict__ Wt, int K, int N)
{
    __shared__ bf16_t tile[32][33];
    const int k0 = blockIdx.x * 32;
    const int n0 = blockIdx.y * 32;
    const int c  = threadIdx.x & 31, r0 = threadIdx.x >> 5;
#pragma unroll
    for (int i = 0; i < 4; ++i) {
        int r = r0 + i * 8;
        tile[r][c] = (bf16_t)W[(size_t)(k0 + r) * N + n0 + c];
    }
    __syncthreads();
#pragma unroll
    for (int i = 0; i < 4; ++i) {
        int r = r0 + i * 8;
        Wt[(size_t)(n0 + r) * K + k0 + c] = tile[c][r];
    }
}

// ---------------------------------------------------------------------------
// Merged K-RoPE (in place) + V transpose (r10-verified).
// ---------------------------------------------------------------------------
__global__ __launch_bounds__(256)
void ropek_vtrans_kernel(bf16_t* __restrict__ kb, int kstr,
                         const bf16_t* __restrict__ Vs, int vstr,
                         bf16_t* __restrict__ Vt,
                         const float* __restrict__ cosT, const float* __restrict__ sinT)
{
    __shared__ bf16_t tile[32][33];
    const int bid = blockIdx.x;
    if (bid < 8192) {
        int lin  = bid * 256 + threadIdx.x;
        int d    = lin & 63;
        int rest = lin >> 6;
        int kvh  = rest & 7;
        int t    = rest >> 3;
        int p    = t & (SEQLEN - 1);
        float c = cosT[p * HEADDIM + d];
        float s = sinT[p * HEADDIM + d];
        bf16_t* ptr = kb + (size_t)t * kstr + kvh * HEADDIM;
        float x1 = (float)ptr[d], x2 = (float)ptr[d + 64];
        ptr[d]      = (bf16_t)(x1 * c - x2 * s);
        ptr[d + 64] = (bf16_t)(x2 * c + x1 * s);
        return;
    }
    int j = bid - 8192;
    const int s0  = (j & 31) * 32;
    const int d0  = ((j >> 5) & 3) * 32;
    const int bk  = j >> 7;
    const int b   = bk >> 3, kvh = bk & 7;
    const int c   = threadIdx.x & 31, r0 = threadIdx.x >> 5;
    const bf16_t* src = Vs + (size_t)(b * SEQLEN + s0) * vstr + kvh * HEADDIM + d0;
#pragma unroll
    for (int i = 0; i < 4; ++i) {
        int r = r0 + i * 8;
        tile[r][c] = src[(size_t)r * vstr + c];
    }
    __syncthreads();
    bf16_t* dst = Vt + ((size_t)(b * N_KVH + kvh) * HEADDIM + d0) * SEQLEN + s0;
#pragma unroll
    for (int i = 0; i < 4; ++i) {
        int dr = r0 + i * 8;
        dst[(size_t)dr * SEQLEN + c] = tile[c][dr];
    }
}

// ---------------------------------------------------------------------------
// Flash attention, 8-wave 32x32 structure with in-register Q-RoPE (r10).
// ---------------------------------------------------------------------------
__device__ __forceinline__ unsigned int pk2(float a, float b)
{
    unsigned short x = __builtin_bit_cast(unsigned short, (bf16_t)a);
    unsigned short y = __builtin_bit_cast(unsigned short, (bf16_t)b);
    return ((unsigned int)y << 16) | (unsigned int)x;
}
__device__ __forceinline__ void swap32(unsigned int& a, unsigned int& b)
{
    asm volatile("v_permlane32_swap_b32 %0, %1" : "+v"(a), "+v"(b));
}

__device__ __forceinline__ void stage_kv(const bf16_t* __restrict__ Kb, int kstr,
                                         const bf16_t* __restrict__ Vt,
                                         char* ldsb, int bb, int kvh, int kb,
                                         int w, int i)
{
#pragma unroll
    for (int j = 0; j < 2; ++j) {
        int row = w * 8 + j * 4 + (i >> 4);
        const bf16_t* src = Kb + (size_t)(bb * SEQLEN + kb + row) * kstr + kvh * HEADDIM
                          + (((i & 15) ^ (row & 7)) << 3);
        llds16(src, (const bf16_t*)(ldsb + (w * 8 + j * 4) * 256));
    }
#pragma unroll
    for (int j = 0; j < 2; ++j) {
        int d = w * 16 + j * 8 + (i >> 3);
        const bf16_t* src = Vt + ((size_t)((bb * N_KVH + kvh) * HEADDIM + d)) * SEQLEN + kb
                          + (((i & 7) ^ (d & 7)) << 3);
        llds16(src, (const bf16_t*)(ldsb + 16384 + (w * 16 + j * 8) * 128));
    }
}

__global__ __launch_bounds__(512, 2)
void attn32_kernel(const bf16_t* __restrict__ Qb, const bf16_t* __restrict__ Kb,
                   const bf16_t* __restrict__ Vt, bf16_t* __restrict__ Ob,
                   int qstr, int kstr,
                   const float* __restrict__ cosT, const float* __restrict__ sinT)
{
    __shared__ __align__(16) char lds[65536];
    const int tid = threadIdx.x, w = tid >> 6, i = tid & 63;
    const int la = i & 31, hi = i >> 5;
    const int qt = blockIdx.x, kvh = blockIdx.y, bb = blockIdx.z;
    const int Q0 = qt * 64;
    const int h  = kvh * 4 + (w >> 1);
    const int qw = Q0 + 32 * (w & 1);
    const int KL = Q0 >= WINDOW ? Q0 - WINDOW : 0;
    const int nt = (Q0 - KL) / 64 + 1;
    const int iq = qw + la;

    const bf16_t* qp = Qb + (size_t)(bb * SEQLEN + iq) * qstr + h * HEADDIM + 8 * hi;
    bf16x8 qf[8];
#pragma unroll
    for (int c = 0; c < 8; ++c) qf[c] = *(const bf16x8*)(qp + c * 16);

    {
        const float sc = 0.08838834764831845f;
        const float* crow = cosT + (size_t)iq * HEADDIM + 8 * hi;
        const float* srow = sinT + (size_t)iq * HEADDIM + 8 * hi;
#pragma unroll
        for (int c = 0; c < 4; ++c) {
            float4 c0 = *(const float4*)(crow + c * 16);
            float4 c1 = *(const float4*)(crow + c * 16 + 4);
            float4 sA = *(const float4*)(srow + c * 16);
            float4 sB = *(const float4*)(srow + c * 16 + 4);
            float cc[8] = {c0.x, c0.y, c0.z, c0.w, c1.x, c1.y, c1.z, c1.w};
            float ss[8] = {sA.x, sA.y, sA.z, sA.w, sB.x, sB.y, sB.z, sB.w};
#pragma unroll
            for (int j = 0; j < 8; ++j) {
                float x1 = (float)qf[c][j], x2 = (float)qf[c + 4][j];
                qf[c][j]     = (bf16_t)((x1 * cc[j] - x2 * ss[j]) * sc);
                qf[c + 4][j] = (bf16_t)((x2 * cc[j] + x1 * ss[j]) * sc);
            }
        }
    }

    f32x16 oacc[4];
#pragma unroll
    for (int d = 0; d < 4; ++d)
#pragma unroll
        for (int r = 0; r < 16; ++r) oacc[d][r] = 0.f;
    float mrow = -1e30f, lsum = 0.f;

    stage_kv(Kb, kstr, Vt, lds, bb, kvh, KL, w, i);

    const int cswz = (la & 7) << 4;

    for (int t = 0; t < nt; ++t) {
        asm volatile("s_waitcnt vmcnt(0) lgkmcnt(0)" ::: "memory");
        __builtin_amdgcn_sched_barrier(0);
        __syncthreads();
        if (t + 1 < nt)
            stage_kv(Kb, kstr, Vt, lds + ((t + 1) & 1) * 32768, bb, kvh, KL + (t + 1) * 64, w, i);
        const char* KsB = lds + (t & 1) * 32768;
        const char* VsB = KsB + 16384;
        const int kb = KL + t * 64;

        f32x16 s0, s1;
#pragma unroll
        for (int r = 0; r < 16; ++r) { s0[r] = 0.f; s1[r] = 0.f; }
        __builtin_amdgcn_s_setprio(1);
#pragma unroll
        for (int c = 0; c < 8; ++c) {
            bf16x8 k0 = *(const bf16x8*)(KsB + la * 256        + ((c * 32 + 16 * hi) ^ cswz));
            bf16x8 k1 = *(const bf16x8*)(KsB + (la + 32) * 256 + ((c * 32 + 16 * hi) ^ cswz));
            s0 = __builtin_amdgcn_mfma_f32_32x32x16_bf16(k0, qf[c], s0, 0, 0, 0);
            s1 = __builtin_amdgcn_mfma_f32_32x32x16_bf16(k1, qf[c], s1, 0, 0, 0);
        }
        __builtin_amdgcn_s_setprio(0);

        const bool interior = (kb + 63 <= qw) && (kb >= qw - (WINDOW - 31));
        if (!interior) {
#pragma unroll
            for (int r = 0; r < 16; ++r) {
                int j0 = kb + (r & 3) + 8 * (r >> 2) + 4 * hi;
                int j1 = j0 + 32;
                if (!(j0 <= iq && iq - j0 <= WINDOW)) s0[r] = -1e30f;
                if (!(j1 <= iq && iq - j1 <= WINDOW)) s1[r] = -1e30f;
            }
        }

        float mt = fmaxf(s0[0], s1[0]);
#pragma unroll
        for (int r = 1; r < 16; ++r) mt = fmaxf(mt, fmaxf(s0[r], s1[r]));
        mt = fmaxf(mt, __shfl_xor(mt, 32, 64));
        float mnew = fmaxf(mrow, mt);
        float corr = __expf(mrow - mnew);
        float ps = 0.f;
#pragma unroll
        for (int r = 0; r < 16; ++r) {
            s0[r] = __expf(s0[r] - mnew);
            s1[r] = __expf(s1[r] - mnew);
            ps += s0[r] + s1[r];
        }
        ps += __shfl_xor(ps, 32, 64);
        lsum = lsum * corr + ps;
        mrow = mnew;
#pragma unroll
        for (int d = 0; d < 4; ++d)
#pragma unroll
            for (int r = 0; r < 16; ++r) oacc[d][r] *= corr;

        bf16x8 pa[4];
        {
            unsigned int w0 = pk2(s0[0], s0[1]),  w1 = pk2(s0[2], s0[3]);
            unsigned int w2 = pk2(s0[4], s0[5]),  w3 = pk2(s0[6], s0[7]);
            swap32(w0, w2); swap32(w1, w3);
            u32x4 u; u[0] = w0; u[1] = w1; u[2] = w2; u[3] = w3;
            pa[0] = __builtin_bit_cast(bf16x8, u);
            w0 = pk2(s0[8], s0[9]);   w1 = pk2(s0[10], s0[11]);
            w2 = pk2(s0[12], s0[13]); w3 = pk2(s0[14], s0[15]);
            swap32(w0, w2); swap32(w1, w3);
            u[0] = w0; u[1] = w1; u[2] = w2; u[3] = w3;
            pa[1] = __builtin_bit_cast(bf16x8, u);
            w0 = pk2(s1[0], s1[1]);  w1 = pk2(s1[2], s1[3]);
            w2 = pk2(s1[4], s1[5]);  w3 = pk2(s1[6], s1[7]);
            swap32(w0, w2); swap32(w1, w3);
            u[0] = w0; u[1] = w1; u[2] = w2; u[3] = w3;
            pa[2] = __builtin_bit_cast(bf16x8, u);
            w0 = pk2(s1[8], s1[9]);   w1 = pk2(s1[10], s1[11]);
            w2 = pk2(s1[12], s1[13]); w3 = pk2(s1[14], s1[15]);
            swap32(w0, w2); swap32(w1, w3);
            u[0] = w0; u[1] = w1; u[2] = w2; u[3] = w3;
            pa[3] = __builtin_bit_cast(bf16x8, u);
        }

        __builtin_amdgcn_s_setprio(1);
#pragma unroll
        for (int d = 0; d < 4; ++d) {
            const char* vrow = VsB + (d * 32 + la) * 128;
#pragma unroll
            for (int ks = 0; ks < 4; ++ks) {
                bf16x8 vf = *(const bf16x8*)(vrow + ((ks * 32 + 16 * hi) ^ cswz));
                oacc[d] = __builtin_amdgcn_mfma_f32_32x32x16_bf16(vf, pa[ks], oacc[d], 0, 0, 0);
            }
        }
        __builtin_amdgcn_s_setprio(0);
    }

    float rn = 1.f / lsum;
    bf16_t* orow = Ob + ((size_t)((bb * SEQLEN + iq) * N_HEADS + h)) * HEADDIM;
#pragma unroll
    for (int d = 0; d < 4; ++d)
#pragma unroll
        for (int g = 0; g < 4; ++g) {
            bf16x4 v;
            v[0] = (bf16_t)(oacc[d][4 * g + 0] * rn);
            v[1] = (bf16_t)(oacc[d][4 * g + 1] * rn);
            v[2] = (bf16_t)(oacc[d][4 * g + 2] * rn);
            v[3] = (bf16_t)(oacc[d][4 * g + 3] * rn);
            *(bf16x4*)(orow + d * 32 + 8 * g + 4 * hi) = v;
        }
}

// ---------------------------------------------------------------------------
extern "C" void kernel_launch(void* const* d_in, const int* in_sizes, int n_in,
                              void* d_out, int out_size, void* d_ws, size_t ws_size,
                              hipStream_t stream)
{
    const float* cosT = (const float*)d_in[0];
    const float* sinT = (const float*)d_in[1];
    const float* x    = (const float*)d_in[2];
    const float* Wq   = (const float*)d_in[6];
    const float* Wk   = (const float*)d_in[7];
    const float* Wv   = (const float*)d_in[8];
    const float* Wo   = (const float*)d_in[9];
    float* out = (float*)d_out;
    char* ws = (char*)d_ws;
    const size_t MB = 1024ull * 1024ull;

    if (ws_size >= 136 * MB) {
        bf16_t* Xb    = (bf16_t*)(ws);            // 32MB; reused as Ob after projections
        bf16_t* Wqkvt = (bf16_t*)(ws + 32 * MB);  // 48MB [6144][4096] (Q|K|V rows)
        bf16_t* Qb    = (bf16_t*)(ws + 80 * MB);  // 32MB [T][4096]
        bf16_t* KVb   = (bf16_t*)(ws + 112 * MB); // 16MB [T][2048] (K|V)
        bf16_t* Vt    = (bf16_t*)(ws + 128 * MB); //  8MB [B][KVH][D][S]
        bf16_t* Ob    = Xb;
        const bool withWo = ws_size >= 168 * MB;
        bf16_t* WoT = withWo ? (bf16_t*)(ws + 136 * MB) : Wqkvt;

        const int prep_blocks = 8192 + 16384 + 4096 + 4096 + (withWo ? 16384 : 0);
        prep_kernel<<<prep_blocks, 256, 0, stream>>>(x, Wq, Wk, Wv, Wo, Xb, Wqkvt, WoT);
        // Q-proj: grid 256 = exactly 1 tail-free round on 8p
        gemm8p_kernel<false><<<dim3((NTOK/256) * (HIDDEN/256)), 512, 0, stream>>>(Xb, Wqkvt, Qb, NTOK, HIDDEN, HIDDEN);
        // KV-proj: grid 128 = one half-machine round on 8p
        gemm8p_kernel<false><<<dim3((NTOK/256) * (KVW/256)), 512, 0, stream>>>(Xb, Wqkvt + (size_t)4096 * HIDDEN, KVb, NTOK, KVW, HIDDEN);
        if (!withWo)
            wtrans_kernel<<<dim3(HIDDEN/32, HIDDEN/32), 256, 0, stream>>>(Wo, Wqkvt, HIDDEN, HIDDEN);
        ropek_vtrans_kernel<<<8192 + 4096, 256, 0, stream>>>(KVb, KVW, KVb + 1024, KVW, Vt, cosT, sinT);
        attn32_kernel<<<dim3(SEQLEN/64, N_KVH, NBATCH), 512, 0, stream>>>(Qb, KVb, Vt, Ob, HIDDEN, KVW, cosT, sinT);
        gemm8p_kernel<true><<<dim3((NTOK/256) * (HIDDEN/256)), 512, 0, stream>>>(Ob, WoT, out, NTOK, HIDDEN, HIDDEN);
    } else {
        bf16_t* Qb = (bf16_t*)(ws);
        bf16_t* Kb = (bf16_t*)(ws + 32 * MB);
        bf16_t* Vb = (bf16_t*)(ws + 40 * MB);
        bf16_t* Vt = (bf16_t*)(ws + 48 * MB);
        bf16_t* Ob = (bf16_t*)(ws + 56 * MB);
        gemm_kernel<true, false><<<dim3(32, 32), 256, 0, stream>>>(x, Wq, Qb, NTOK, HIDDEN, HIDDEN);
        gemm_kernel<true, false><<<dim3(8, 32), 256, 0, stream>>>(x, Wk, Kb, NTOK, 1024, HIDDEN);
        gemm_kernel<true, false><<<dim3(8, 32), 256, 0, stream>>>(x, Wv, Vb, NTOK, 1024, HIDDEN);
        ropek_vtrans_kernel<<<8192 + 4096, 256, 0, stream>>>(Kb, 1024, Vb, 1024, Vt, cosT, sinT);
        attn32_kernel<<<dim3(SEQLEN/64, N_KVH, NBATCH), 512, 0, stream>>>(Qb, Kb, Vt, Ob, HIDDEN, 1024, cosT, sinT);
        gemm_kernel<false, true><<<dim3(32, 32), 256, 0, stream>>>(Ob, Wo, out, NTOK, HIDDEN, HIDDEN);
    }
}

// Round 14
// 476.867 us; speedup vs baseline: 1.0413x; 1.0413x over previous
//
#include <hip/hip_runtime.h>

typedef __bf16 bf16_t;
typedef __bf16 bf16x8 __attribute__((ext_vector_type(8)));
typedef __bf16 bf16x4 __attribute__((ext_vector_type(4)));
typedef float  f32x4  __attribute__((ext_vector_type(4)));
typedef float  f32x16 __attribute__((ext_vector_type(16)));
typedef unsigned int u32x4 __attribute__((ext_vector_type(4)));

#define N_HEADS 32
#define N_KVH   8
#define HEADDIM 128
#define WINDOW  512
#define NBATCH  4
#define SEQLEN  1024
#define NTOK    (NBATCH * SEQLEN)
#define HIDDEN  4096
#define QKVW    6144   /* fused QKV row width: 4096 Q + 1024 K + 1024 V */

// async global->LDS, 16B per lane. LDS dest is wave-uniform base + lane*16.
__device__ __forceinline__ void llds16(const bf16_t* g, const bf16_t* l)
{
    __builtin_amdgcn_global_load_lds(
        (const __attribute__((address_space(1))) void*)g,
        (__attribute__((address_space(3))) void*)l, 16, 0, 0);
}

#define MFMA16(a, b, c) __builtin_amdgcn_mfma_f32_16x16x32_bf16((a), (b), (c), 0, 0, 0)

// ---------------------------------------------------------------------------
// 256x128-tile dual-occupancy GEMM (r9-verified: QKV 206us @45%): 2 blocks/CU
// backfills the 768-block QKV grid. Best measured QKV structure (r9-r13 A/B:
// dual 206-221 vs 256^2 224 vs 8p 247 vs split 231).
// ---------------------------------------------------------------------------
template<bool OUT_F32>
__global__ __launch_bounds__(512, 4)
void gemm_dual_kernel(const bf16_t* __restrict__ A, const bf16_t* __restrict__ Bt,
                      void* __restrict__ Cp, int M, int N, int K)
{
    __shared__ __align__(16) char lds[3 * 24576];
    const int tid  = threadIdx.x;
    const int w    = tid >> 6, lane = tid & 63;
    const int ntx  = N >> 7;
    const int nwg  = gridDim.x;
    const int cpx  = nwg >> 3;
    const int lin  = blockIdx.x;
    const int swz  = (nwg & 7) == 0 ? (lin & 7) * cpx + (lin >> 3) : lin;
    const int m0   = (swz / ntx) * 256;
    const int n0   = (swz % ntx) * 128;
    const int wm   = (w >> 1) * 64;
    const int wn   = (w & 1) * 64;
    const int fr   = lane & 15;
    const int kslot16 = (((lane >> 4) ^ ((lane >> 1) & 3)) << 4);
    const int srcblk  = (((tid & 3) ^ ((tid >> 3) & 3)) << 3);
    const int nk = K >> 5;

    f32x4 acc[4][4];
#pragma unroll
    for (int i = 0; i < 4; ++i)
#pragma unroll
        for (int j = 0; j < 4; ++j) {
            acc[i][j][0] = 0.f; acc[i][j][1] = 0.f;
            acc[i][j][2] = 0.f; acc[i][j][3] = 0.f;
        }

    const bf16_t* arow = A  + (size_t)(m0 + (tid >> 2)) * K + srcblk;
    const bf16_t* brow = Bt + (size_t)(n0 + (tid >> 2)) * K + srcblk;
    const size_t rowK128 = (size_t)128 * K;

    auto STAGE = [&](int tt, int buf) {
        char* dst = lds + buf * 24576 + w * 1024;
        const int kt = tt << 5;
        llds16(arow + kt,           (const bf16_t*)(dst));
        llds16(arow + rowK128 + kt, (const bf16_t*)(dst + 8192));
        llds16(brow + kt,           (const bf16_t*)(dst + 16384));
    };

    STAGE(0, 0); STAGE(1, 1);

    int cur = 0;
    for (int t = 0; t < nk; ++t) {
        if (t + 1 < nk) asm volatile("s_waitcnt vmcnt(3)" ::: "memory");
        else            asm volatile("s_waitcnt vmcnt(0)" ::: "memory");
        __builtin_amdgcn_sched_barrier(0);
        __builtin_amdgcn_s_barrier();
        __builtin_amdgcn_sched_barrier(0);

        const char* base = lds + cur * 24576;
        bf16x8 af[4], bfg[4];
#pragma unroll
        for (int mt = 0; mt < 4; ++mt)
            af[mt] = *(const bf16x8*)(base + ((wm + mt * 16 + fr) << 6) + kslot16);
#pragma unroll
        for (int nt = 0; nt < 4; ++nt)
            bfg[nt] = *(const bf16x8*)(base + 16384 + ((wn + nt * 16 + fr) << 6) + kslot16);

        if (t + 2 < nk) {
            int nb = cur + 2; if (nb >= 3) nb -= 3;
            STAGE(t + 2, nb);
        }
        __builtin_amdgcn_s_setprio(1);
#pragma unroll
        for (int mt = 0; mt < 4; ++mt)
#pragma unroll
            for (int nt = 0; nt < 4; ++nt)
                acc[mt][nt] = MFMA16(af[mt], bfg[nt], acc[mt][nt]);
        __builtin_amdgcn_s_setprio(0);
        ++cur; if (cur == 3) cur = 0;
    }

    const int r0 = (lane >> 4) << 2;
#pragma unroll
    for (int mt = 0; mt < 4; ++mt)
#pragma unroll
        for (int nt = 0; nt < 4; ++nt)
#pragma unroll
            for (int r = 0; r < 4; ++r) {
                int row = m0 + wm + mt * 16 + r0 + r;
                int col = n0 + wn + nt * 16 + fr;
                if constexpr (OUT_F32)
                    ((float*)Cp)[(size_t)row * N + col] = acc[mt][nt][r];
                else
                    ((bf16_t*)Cp)[(size_t)row * N + col] = (bf16_t)acc[mt][nt][r];
            }
}

// ---------------------------------------------------------------------------
// 256x256-tile 4-deep pipelined GEMM (r5/r8-verified: out-proj 122us @49%).
// Best measured structure for tail-free 1-round grids (out-proj grid 256).
// ---------------------------------------------------------------------------
template<bool OUT_F32>
__global__ __launch_bounds__(512, 2)
void gemm256_kernel(const bf16_t* __restrict__ A, const bf16_t* __restrict__ Bt,
                    void* __restrict__ Cp, int M, int N, int K)
{
    __shared__ __align__(16) char lds[4 * 32768];   // 4 bufs x (A 16KB + B 16KB)
    const int tid  = threadIdx.x;
    const int w    = tid >> 6, lane = tid & 63;
    const int ntx  = N >> 8;
    const int nwg  = gridDim.x;
    const int cpx  = nwg >> 3;
    const int lin  = blockIdx.x;
    const int swz  = (nwg & 7) == 0 ? (lin & 7) * cpx + (lin >> 3) : lin;
    const int m0   = (swz / ntx) * 256;
    const int n0   = (swz % ntx) * 256;
    const int wm   = (w >> 2) * 128;
    const int wn   = (w & 3) * 64;
    const int fr   = lane & 15;
    const int kslot16 = (((lane >> 4) ^ ((lane >> 1) & 3)) << 4);
    const int srcblk  = (((tid & 3) ^ ((tid >> 3) & 3)) << 3);
    const int nk = K >> 5;

    f32x4 acc[8][4];
#pragma unroll
    for (int i = 0; i < 8; ++i)
#pragma unroll
        for (int j = 0; j < 4; ++j) {
            acc[i][j][0] = 0.f; acc[i][j][1] = 0.f;
            acc[i][j][2] = 0.f; acc[i][j][3] = 0.f;
        }

    const bf16_t* arow = A  + (size_t)(m0 + (tid >> 2)) * K + srcblk;
    const bf16_t* brow = Bt + (size_t)(n0 + (tid >> 2)) * K + srcblk;
    const size_t rowK128 = (size_t)128 * K;

    auto STAGE = [&](int tt) {
        char* dst = lds + (tt & 3) * 32768 + w * 1024;
        const int kt = tt << 5;
#pragma unroll
        for (int j = 0; j < 2; ++j)
            llds16(arow + j * rowK128 + kt, (const bf16_t*)(dst + j * 8192));
#pragma unroll
        for (int j = 0; j < 2; ++j)
            llds16(brow + j * rowK128 + kt, (const bf16_t*)(dst + 16384 + j * 8192));
    };

    STAGE(0); STAGE(1); STAGE(2);

    for (int t = 0; t < nk; ++t) {
        if (t < nk - 2)       asm volatile("s_waitcnt vmcnt(8)" ::: "memory");
        else if (t == nk - 2) asm volatile("s_waitcnt vmcnt(4)" ::: "memory");
        else                  asm volatile("s_waitcnt vmcnt(0)" ::: "memory");
        __builtin_amdgcn_sched_barrier(0);
        __builtin_amdgcn_s_barrier();
        __builtin_amdgcn_sched_barrier(0);

        const char* base = lds + (t & 3) * 32768;
        bf16x8 af[8], bfg[4];
#pragma unroll
        for (int mt = 0; mt < 8; ++mt)
            af[mt] = *(const bf16x8*)(base + ((wm + mt * 16 + fr) << 6) + kslot16);
#pragma unroll
        for (int nt = 0; nt < 4; ++nt)
            bfg[nt] = *(const bf16x8*)(base + 16384 + ((wn + nt * 16 + fr) << 6) + kslot16);

        if (t + 3 < nk) STAGE(t + 3);
        __builtin_amdgcn_s_setprio(1);
#pragma unroll
        for (int mt = 0; mt < 8; ++mt)
#pragma unroll
            for (int nt = 0; nt < 4; ++nt)
                acc[mt][nt] = MFMA16(af[mt], bfg[nt], acc[mt][nt]);
        __builtin_amdgcn_s_setprio(0);
    }

    const int r0 = (lane >> 4) << 2;
#pragma unroll
    for (int mt = 0; mt < 8; ++mt)
#pragma unroll
        for (int nt = 0; nt < 4; ++nt)
#pragma unroll
            for (int r = 0; r < 4; ++r) {
                int row = m0 + wm + mt * 16 + r0 + r;
                int col = n0 + wn + nt * 16 + fr;
                if constexpr (OUT_F32)
                    ((float*)Cp)[(size_t)row * N + col] = acc[mt][nt][r];
                else
                    ((bf16_t*)Cp)[(size_t)row * N + col] = (bf16_t)acc[mt][nt][r];
            }
}

// ---------------------------------------------------------------------------
// fallback GEMM: A f32 or bf16, B f32 [K][N] transposed in LDS
// ---------------------------------------------------------------------------
template<bool A_F32, bool OUT_F32>
__global__ __launch_bounds__(256)
void gemm_kernel(const void* __restrict__ Ap, const void* __restrict__ Bp,
                 void* __restrict__ Cp, int M, int N, int K)
{
    __shared__ bf16_t As[128 * 40];
    __shared__ bf16_t Bs[128 * 40];
    const int tid  = threadIdx.x;
    const int m0   = blockIdx.y * 128;
    const int n0   = blockIdx.x * 128;
    const int wave = tid >> 6, lane = tid & 63;
    const int wm   = (wave >> 1) * 64, wn = (wave & 1) * 64;
    const int fr   = lane & 15;
    const int koff = (lane >> 4) * 8;

    f32x4 acc[4][4];
#pragma unroll
    for (int i = 0; i < 4; ++i)
#pragma unroll
        for (int j = 0; j < 4; ++j) {
            acc[i][j][0] = 0.f; acc[i][j][1] = 0.f;
            acc[i][j][2] = 0.f; acc[i][j][3] = 0.f;
        }

    for (int kt = 0; kt < K; kt += 32) {
        __syncthreads();
        if constexpr (A_F32) {
            const float* A = (const float*)Ap;
#pragma unroll
            for (int i = 0; i < 4; ++i) {
                int lin = tid + i * 256;
                int row = lin >> 3;
                int kq  = (lin & 7) << 2;
                const float4 v = *(const float4*)(A + (size_t)(m0 + row) * K + kt + kq);
                bf16_t* d = &As[row * 40 + kq];
                d[0] = (bf16_t)v.x; d[1] = (bf16_t)v.y;
                d[2] = (bf16_t)v.z; d[3] = (bf16_t)v.w;
            }
        } else {
            const bf16_t* A = (const bf16_t*)Ap;
#pragma unroll
            for (int i = 0; i < 2; ++i) {
                int lin = tid + i * 256;
                int row = lin >> 2;
                int kq  = (lin & 3) << 3;
                *(bf16x8*)&As[row * 40 + kq] =
                    *(const bf16x8*)(A + (size_t)(m0 + row) * K + kt + kq);
            }
        }
        {
            const float* B = (const float*)Bp;
#pragma unroll
            for (int i = 0; i < 4; ++i) {
                int lin = tid + i * 256;
                int kr  = lin >> 5;
                int nc  = (lin & 31) << 2;
                const float4 v = *(const float4*)(B + (size_t)(kt + kr) * N + n0 + nc);
                Bs[(nc + 0) * 40 + kr] = (bf16_t)v.x;
                Bs[(nc + 1) * 40 + kr] = (bf16_t)v.y;
                Bs[(nc + 2) * 40 + kr] = (bf16_t)v.z;
                Bs[(nc + 3) * 40 + kr] = (bf16_t)v.w;
            }
        }
        __syncthreads();
        bf16x8 af[4], bfg[4];
#pragma unroll
        for (int mt = 0; mt < 4; ++mt)
            af[mt] = *(const bf16x8*)&As[(wm + mt * 16 + fr) * 40 + koff];
#pragma unroll
        for (int nt = 0; nt < 4; ++nt)
            bfg[nt] = *(const bf16x8*)&Bs[(wn + nt * 16 + fr) * 40 + koff];
#pragma unroll
        for (int mt = 0; mt < 4; ++mt)
#pragma unroll
            for (int nt = 0; nt < 4; ++nt)
                acc[mt][nt] = MFMA16(af[mt], bfg[nt], acc[mt][nt]);
    }
    const int r0 = (lane >> 4) << 2;
#pragma unroll
    for (int mt = 0; mt < 4; ++mt)
#pragma unroll
        for (int nt = 0; nt < 4; ++nt)
#pragma unroll
            for (int r = 0; r < 4; ++r) {
                int row = m0 + wm + mt * 16 + r0 + r;
                int col = n0 + wn + nt * 16 + fr;
                if constexpr (OUT_F32)
                    ((float*)Cp)[(size_t)row * N + col] = acc[mt][nt][r];
                else
                    ((bf16_t*)Cp)[(size_t)row * N + col] = (bf16_t)acc[mt][nt][r];
            }
}

// ---------------------------------------------------------------------------
// Merged prep: x f32->bf16 + Wq/Wk/Wv (+Wo) transpose-convert (r10-verified).
// ---------------------------------------------------------------------------
__global__ __launch_bounds__(256)
void prep_kernel(const float* __restrict__ x,
                 const float* __restrict__ Wq, const float* __restrict__ Wk,
                 const float* __restrict__ Wv, const float* __restrict__ Wo,
                 bf16_t* __restrict__ Xb, bf16_t* __restrict__ Wqkvt,
                 bf16_t* __restrict__ WoT)
{
    __shared__ bf16_t tile[32][33];
    const int bid = blockIdx.x;
    if (bid < 8192) {
        int i = bid * 256 + threadIdx.x;
        const float4 a = *(const float4*)(x + (size_t)i * 8);
        const float4 b = *(const float4*)(x + (size_t)i * 8 + 4);
        bf16x8 v;
        v[0] = (bf16_t)a.x; v[1] = (bf16_t)a.y; v[2] = (bf16_t)a.z; v[3] = (bf16_t)a.w;
        v[4] = (bf16_t)b.x; v[5] = (bf16_t)b.y; v[6] = (bf16_t)b.z; v[7] = (bf16_t)b.w;
        *(bf16x8*)(Xb + (size_t)i * 8) = v;
        return;
    }
    const float* W; bf16_t* Wt; int j;
    if (bid < 24576)      { W = Wq; Wt = Wqkvt;                          j = bid - 8192; }
    else if (bid < 28672) { W = Wk; Wt = Wqkvt + (size_t)4096 * HIDDEN;  j = bid - 24576; }
    else if (bid < 32768) { W = Wv; Wt = Wqkvt + (size_t)5120 * HIDDEN;  j = bid - 28672; }
    else                  { W = Wo; Wt = WoT;                            j = bid - 32768; }
    const int N  = (bid >= 24576 && bid < 32768) ? 1024 : HIDDEN;
    const int k0 = (j & 127) << 5;
    const int n0 = (j >> 7) << 5;
    const int c  = threadIdx.x & 31, r0 = threadIdx.x >> 5;
#pragma unroll
    for (int i = 0; i < 4; ++i) {
        int r = r0 + i * 8;
        tile[r][c] = (bf16_t)W[(size_t)(k0 + r) * N + n0 + c];
    }
    __syncthreads();
#pragma unroll
    for (int i = 0; i < 4; ++i) {
        int r = r0 + i * 8;
        Wt[(size_t)(n0 + r) * HIDDEN + k0 + c] = tile[c][r];
    }
}

__global__ __launch_bounds__(256)
void wtrans_kernel(const float* __restrict__ W, bf16_t* __restrict__ Wt, int K, int N)
{
    __shared__ bf16_t tile[32][33];
    const int k0 = blockIdx.x * 32;
    const int n0 = blockIdx.y * 32;
    const int c  = threadIdx.x & 31, r0 = threadIdx.x >> 5;
#pragma unroll
    for (int i = 0; i < 4; ++i) {
        int r = r0 + i * 8;
        tile[r][c] = (bf16_t)W[(size_t)(k0 + r) * N + n0 + c];
    }
    __syncthreads();
#pragma unroll
    for (int i = 0; i < 4; ++i) {
        int r = r0 + i * 8;
        Wt[(size_t)(n0 + r) * K + k0 + c] = tile[c][r];
    }
}

// ---------------------------------------------------------------------------
// Merged K-RoPE (in place) + V transpose (r10-verified).
// ---------------------------------------------------------------------------
__global__ __launch_bounds__(256)
void ropek_vtrans_kernel(bf16_t* __restrict__ kb, int kstr,
                         const bf16_t* __restrict__ Vs, int vstr,
                         bf16_t* __restrict__ Vt,
                         const float* __restrict__ cosT, const float* __restrict__ sinT)
{
    __shared__ bf16_t tile[32][33];
    const int bid = blockIdx.x;
    if (bid < 8192) {
        int lin  = bid * 256 + threadIdx.x;
        int d    = lin & 63;
        int rest = lin >> 6;
        int kvh  = rest & 7;
        int t    = rest >> 3;
        int p    = t & (SEQLEN - 1);
        float c = cosT[p * HEADDIM + d];
        float s = sinT[p * HEADDIM + d];
        bf16_t* ptr = kb + (size_t)t * kstr + kvh * HEADDIM;
        float x1 = (float)ptr[d], x2 = (float)ptr[d + 64];
        ptr[d]      = (bf16_t)(x1 * c - x2 * s);
        ptr[d + 64] = (bf16_t)(x2 * c + x1 * s);
        return;
    }
    int j = bid - 8192;
    const int s0  = (j & 31) * 32;
    const int d0  = ((j >> 5) & 3) * 32;
    const int bk  = j >> 7;
    const int b   = bk >> 3, kvh = bk & 7;
    const int c   = threadIdx.x & 31, r0 = threadIdx.x >> 5;
    const bf16_t* src = Vs + (size_t)(b * SEQLEN + s0) * vstr + kvh * HEADDIM + d0;
#pragma unroll
    for (int i = 0; i < 4; ++i) {
        int r = r0 + i * 8;
        tile[r][c] = src[(size_t)r * vstr + c];
    }
    __syncthreads();
    bf16_t* dst = Vt + ((size_t)(b * N_KVH + kvh) * HEADDIM + d0) * SEQLEN + s0;
#pragma unroll
    for (int i = 0; i < 4; ++i) {
        int dr = r0 + i * 8;
        dst[(size_t)dr * SEQLEN + c] = tile[c][dr];
    }
}

// ---------------------------------------------------------------------------
// Flash attention, 8-wave 32x32 structure with in-register Q-RoPE (r10).
// ---------------------------------------------------------------------------
__device__ __forceinline__ unsigned int pk2(float a, float b)
{
    unsigned short x = __builtin_bit_cast(unsigned short, (bf16_t)a);
    unsigned short y = __builtin_bit_cast(unsigned short, (bf16_t)b);
    return ((unsigned int)y << 16) | (unsigned int)x;
}
__device__ __forceinline__ void swap32(unsigned int& a, unsigned int& b)
{
    asm volatile("v_permlane32_swap_b32 %0, %1" : "+v"(a), "+v"(b));
}

__device__ __forceinline__ void stage_kv(const bf16_t* __restrict__ Kb, int kstr,
                                         const bf16_t* __restrict__ Vt,
                                         char* ldsb, int bb, int kvh, int kb,
                                         int w, int i)
{
#pragma unroll
    for (int j = 0; j < 2; ++j) {
        int row = w * 8 + j * 4 + (i >> 4);
        const bf16_t* src = Kb + (size_t)(bb * SEQLEN + kb + row) * kstr + kvh * HEADDIM
                          + (((i & 15) ^ (row & 7)) << 3);
        llds16(src, (const bf16_t*)(ldsb + (w * 8 + j * 4) * 256));
    }
#pragma unroll
    for (int j = 0; j < 2; ++j) {
        int d = w * 16 + j * 8 + (i >> 3);
        const bf16_t* src = Vt + ((size_t)((bb * N_KVH + kvh) * HEADDIM + d)) * SEQLEN + kb
                          + (((i & 7) ^ (d & 7)) << 3);
        llds16(src, (const bf16_t*)(ldsb + 16384 + (w * 16 + j * 8) * 128));
    }
}

__global__ __launch_bounds__(512, 2)
void attn32_kernel(const bf16_t* __restrict__ Qb, const bf16_t* __restrict__ Kb,
                   const bf16_t* __restrict__ Vt, bf16_t* __restrict__ Ob,
                   int qstr, int kstr,
                   const float* __restrict__ cosT, const float* __restrict__ sinT)
{
    __shared__ __align__(16) char lds[65536];
    const int tid = threadIdx.x, w = tid >> 6, i = tid & 63;
    const int la = i & 31, hi = i >> 5;
    const int qt = blockIdx.x, kvh = blockIdx.y, bb = blockIdx.z;
    const int Q0 = qt * 64;
    const int h  = kvh * 4 + (w >> 1);
    const int qw = Q0 + 32 * (w & 1);
    const int KL = Q0 >= WINDOW ? Q0 - WINDOW : 0;
    const int nt = (Q0 - KL) / 64 + 1;
    const int iq = qw + la;

    const bf16_t* qp = Qb + (size_t)(bb * SEQLEN + iq) * qstr + h * HEADDIM + 8 * hi;
    bf16x8 qf[8];
#pragma unroll
    for (int c = 0; c < 8; ++c) qf[c] = *(const bf16x8*)(qp + c * 16);

    {
        const float sc = 0.08838834764831845f;
        const float* crow = cosT + (size_t)iq * HEADDIM + 8 * hi;
        const float* srow = sinT + (size_t)iq * HEADDIM + 8 * hi;
#pragma unroll
        for (int c = 0; c < 4; ++c) {
            float4 c0 = *(const float4*)(crow + c * 16);
            float4 c1 = *(const float4*)(crow + c * 16 + 4);
            float4 sA = *(const float4*)(srow + c * 16);
            float4 sB = *(const float4*)(srow + c * 16 + 4);
            float cc[8] = {c0.x, c0.y, c0.z, c0.w, c1.x, c1.y, c1.z, c1.w};
            float ss[8] = {sA.x, sA.y, sA.z, sA.w, sB.x, sB.y, sB.z, sB.w};
#pragma unroll
            for (int j = 0; j < 8; ++j) {
                float x1 = (float)qf[c][j], x2 = (float)qf[c + 4][j];
                qf[c][j]     = (bf16_t)((x1 * cc[j] - x2 * ss[j]) * sc);
                qf[c + 4][j] = (bf16_t)((x2 * cc[j] + x1 * ss[j]) * sc);
            }
        }
    }

    f32x16 oacc[4];
#pragma unroll
    for (int d = 0; d < 4; ++d)
#pragma unroll
        for (int r = 0; r < 16; ++r) oacc[d][r] = 0.f;
    float mrow = -1e30f, lsum = 0.f;

    stage_kv(Kb, kstr, Vt, lds, bb, kvh, KL, w, i);

    const int cswz = (la & 7) << 4;

    for (int t = 0; t < nt; ++t) {
        asm volatile("s_waitcnt vmcnt(0) lgkmcnt(0)" ::: "memory");
        __builtin_amdgcn_sched_barrier(0);
        __syncthreads();
        if (t + 1 < nt)
            stage_kv(Kb, kstr, Vt, lds + ((t + 1) & 1) * 32768, bb, kvh, KL + (t + 1) * 64, w, i);
        const char* KsB = lds + (t & 1) * 32768;
        const char* VsB = KsB + 16384;
        const int kb = KL + t * 64;

        f32x16 s0, s1;
#pragma unroll
        for (int r = 0; r < 16; ++r) { s0[r] = 0.f; s1[r] = 0.f; }
        __builtin_amdgcn_s_setprio(1);
#pragma unroll
        for (int c = 0; c < 8; ++c) {
            bf16x8 k0 = *(const bf16x8*)(KsB + la * 256        + ((c * 32 + 16 * hi) ^ cswz));
            bf16x8 k1 = *(const bf16x8*)(KsB + (la + 32) * 256 + ((c * 32 + 16 * hi) ^ cswz));
            s0 = __builtin_amdgcn_mfma_f32_32x32x16_bf16(k0, qf[c], s0, 0, 0, 0);
            s1 = __builtin_amdgcn_mfma_f32_32x32x16_bf16(k1, qf[c], s1, 0, 0, 0);
        }
        __builtin_amdgcn_s_setprio(0);

        const bool interior = (kb + 63 <= qw) && (kb >= qw - (WINDOW - 31));
        if (!interior) {
#pragma unroll
            for (int r = 0; r < 16; ++r) {
                int j0 = kb + (r & 3) + 8 * (r >> 2) + 4 * hi;
                int j1 = j0 + 32;
                if (!(j0 <= iq && iq - j0 <= WINDOW)) s0[r] = -1e30f;
                if (!(j1 <= iq && iq - j1 <= WINDOW)) s1[r] = -1e30f;
            }
        }

        float mt = fmaxf(s0[0], s1[0]);
#pragma unroll
        for (int r = 1; r < 16; ++r) mt = fmaxf(mt, fmaxf(s0[r], s1[r]));
        mt = fmaxf(mt, __shfl_xor(mt, 32, 64));
        float mnew = fmaxf(mrow, mt);
        float corr = __expf(mrow - mnew);
        float ps = 0.f;
#pragma unroll
        for (int r = 0; r < 16; ++r) {
            s0[r] = __expf(s0[r] - mnew);
            s1[r] = __expf(s1[r] - mnew);
            ps += s0[r] + s1[r];
        }
        ps += __shfl_xor(ps, 32, 64);
        lsum = lsum * corr + ps;
        mrow = mnew;
#pragma unroll
        for (int d = 0; d < 4; ++d)
#pragma unroll
            for (int r = 0; r < 16; ++r) oacc[d][r] *= corr;

        bf16x8 pa[4];
        {
            unsigned int w0 = pk2(s0[0], s0[1]),  w1 = pk2(s0[2], s0[3]);
            unsigned int w2 = pk2(s0[4], s0[5]),  w3 = pk2(s0[6], s0[7]);
            swap32(w0, w2); swap32(w1, w3);
            u32x4 u; u[0] = w0; u[1] = w1; u[2] = w2; u[3] = w3;
            pa[0] = __builtin_bit_cast(bf16x8, u);
            w0 = pk2(s0[8], s0[9]);   w1 = pk2(s0[10], s0[11]);
            w2 = pk2(s0[12], s0[13]); w3 = pk2(s0[14], s0[15]);
            swap32(w0, w2); swap32(w1, w3);
            u[0] = w0; u[1] = w1; u[2] = w2; u[3] = w3;
            pa[1] = __builtin_bit_cast(bf16x8, u);
            w0 = pk2(s1[0], s1[1]);  w1 = pk2(s1[2], s1[3]);
            w2 = pk2(s1[4], s1[5]);  w3 = pk2(s1[6], s1[7]);
            swap32(w0, w2); swap32(w1, w3);
            u[0] = w0; u[1] = w1; u[2] = w2; u[3] = w3;
            pa[2] = __builtin_bit_cast(bf16x8, u);
            w0 = pk2(s1[8], s1[9]);   w1 = pk2(s1[10], s1[11]);
            w2 = pk2(s1[12], s1[13]); w3 = pk2(s1[14], s1[15]);
            swap32(w0, w2); swap32(w1, w3);
            u[0] = w0; u[1] = w1; u[2] = w2; u[3] = w3;
            pa[3] = __builtin_bit_cast(bf16x8, u);
        }

        __builtin_amdgcn_s_setprio(1);
#pragma unroll
        for (int d = 0; d < 4; ++d) {
            const char* vrow = VsB + (d * 32 + la) * 128;
#pragma unroll
            for (int ks = 0; ks < 4; ++ks) {
                bf16x8 vf = *(const bf16x8*)(vrow + ((ks * 32 + 16 * hi) ^ cswz));
                oacc[d] = __builtin_amdgcn_mfma_f32_32x32x16_bf16(vf, pa[ks], oacc[d], 0, 0, 0);
            }
        }
        __builtin_amdgcn_s_setprio(0);
    }

    float rn = 1.f / lsum;
    bf16_t* orow = Ob + ((size_t)((bb * SEQLEN + iq) * N_HEADS + h)) * HEADDIM;
#pragma unroll
    for (int d = 0; d < 4; ++d)
#pragma unroll
        for (int g = 0; g < 4; ++g) {
            bf16x4 v;
            v[0] = (bf16_t)(oacc[d][4 * g + 0] * rn);
            v[1] = (bf16_t)(oacc[d][4 * g + 1] * rn);
            v[2] = (bf16_t)(oacc[d][4 * g + 2] * rn);
            v[3] = (bf16_t)(oacc[d][4 * g + 3] * rn);
            *(bf16x4*)(orow + d * 32 + 8 * g + 4 * hi) = v;
        }
}

// ---------------------------------------------------------------------------
extern "C" void kernel_launch(void* const* d_in, const int* in_sizes, int n_in,
                              void* d_out, int out_size, void* d_ws, size_t ws_size,
                              hipStream_t stream)
{
    const float* cosT = (const float*)d_in[0];
    const float* sinT = (const float*)d_in[1];
    const float* x    = (const float*)d_in[2];
    const float* Wq   = (const float*)d_in[6];
    const float* Wk   = (const float*)d_in[7];
    const float* Wv   = (const float*)d_in[8];
    const float* Wo   = (const float*)d_in[9];
    float* out = (float*)d_out;
    char* ws = (char*)d_ws;
    const size_t MB = 1024ull * 1024ull;

    if (ws_size >= 136 * MB) {
        bf16_t* Xb    = (bf16_t*)(ws);            // 32MB; reused as Ob after QKV
        bf16_t* Wqkvt = (bf16_t*)(ws + 32 * MB);  // 48MB [6144][4096]
        bf16_t* QKVb  = (bf16_t*)(ws + 80 * MB);  // 48MB [T][6144] (Q|K|V)
        bf16_t* Vt    = (bf16_t*)(ws + 128 * MB); //  8MB [B][KVH][D][S]
        bf16_t* Ob    = Xb;
        const bool withWo = ws_size >= 168 * MB;
        bf16_t* WoT = withWo ? (bf16_t*)(ws + 136 * MB) : Wqkvt;

        const int prep_blocks = 8192 + 16384 + 4096 + 4096 + (withWo ? 16384 : 0);
        prep_kernel<<<prep_blocks, 256, 0, stream>>>(x, Wq, Wk, Wv, Wo, Xb, Wqkvt, WoT);
        gemm_dual_kernel<false><<<dim3((NTOK/256) * (QKVW/128)), 512, 0, stream>>>(Xb, Wqkvt, QKVb, NTOK, QKVW, HIDDEN);
        if (!withWo)
            wtrans_kernel<<<dim3(HIDDEN/32, HIDDEN/32), 256, 0, stream>>>(Wo, Wqkvt, HIDDEN, HIDDEN);
        ropek_vtrans_kernel<<<8192 + 4096, 256, 0, stream>>>(QKVb + 4096, QKVW, QKVb + 5120, QKVW, Vt, cosT, sinT);
        attn32_kernel<<<dim3(SEQLEN/64, N_KVH, NBATCH), 512, 0, stream>>>(QKVb, QKVb + 4096, Vt, Ob, QKVW, QKVW, cosT, sinT);
        gemm256_kernel<true><<<dim3((NTOK/256) * (HIDDEN/256)), 512, 0, stream>>>(Ob, WoT, out, NTOK, HIDDEN, HIDDEN);
    } else {
        bf16_t* Qb = (bf16_t*)(ws);
        bf16_t* Kb = (bf16_t*)(ws + 32 * MB);
        bf16_t* Vb = (bf16_t*)(ws + 40 * MB);
        bf16_t* Vt = (bf16_t*)(ws + 48 * MB);
        bf16_t* Ob = (bf16_t*)(ws + 56 * MB);
        gemm_kernel<true, false><<<dim3(32, 32), 256, 0, stream>>>(x, Wq, Qb, NTOK, HIDDEN, HIDDEN);
        gemm_kernel<true, false><<<dim3(8, 32), 256, 0, stream>>>(x, Wk, Kb, NTOK, 1024, HIDDEN);
        gemm_kernel<true, false><<<dim3(8, 32), 256, 0, stream>>>(x, Wv, Vb, NTOK, 1024, HIDDEN);
        ropek_vtrans_kernel<<<8192 + 4096, 256, 0, stream>>>(Kb, 1024, Vb, 1024, Vt, cosT, sinT);
        attn32_kernel<<<dim3(SEQLEN/64, N_KVH, NBATCH), 512, 0, stream>>>(Qb, Kb, Vt, Ob, HIDDEN, 1024, cosT, sinT);
        gemm_kernel<false, true><<<dim3(32, 32), 256, 0, stream>>>(Ob, Wo, out, NTOK, HIDDEN, HIDDEN);
    }
}